// Round 5
// baseline (105.455 us; speedup 1.0000x reference)
//
#include <hip/hip_runtime.h>
#include <math.h>

#define NBS 2
#define NPTS 4096
#define HH 64
#define WW 192
#define HW (HH*WW)        // 12288
#define NC 64
#define CH 16             // point chunks
#define CSZ (NPTS/CH)     // 256
#define NTILES (HW/64)    // 192

#define FBIG 3.0e38f

// sorted top-3 insert, strict < (ties keep earlier => lower index wins,
// matching lax.top_k, given ascending-index encounter order)
#define INSERT3(dv, gi)                                   \
  if ((dv) < v2) {                                        \
    if ((dv) < v1) {                                      \
      v2 = v1; i2 = i1;                                   \
      if ((dv) < v0) { v1 = v0; i1 = i0; v0 = (dv); i0 = (gi); } \
      else           { v1 = (dv); i1 = (gi); }            \
    } else { v2 = (dv); i2 = (gi); }                      \
  }

// ---------------- K0: pack points (2u0,2u1,uu) + transpose feat_3d ----------
__global__ __launch_bounds__(256) void k0_prep(
    const float* __restrict__ uv, const float* __restrict__ f3d,
    float4* __restrict__ pts, float* __restrict__ f3dT) {
#pragma clang fp contract(off)
  int bid = blockIdx.x;
  int t = threadIdx.x;
  if (bid < 128) {
    // transpose 64n x 64c tile: b = bid/64, ntile = bid%64
    int b = bid >> 6;
    int nt = (bid & 63) << 6;
    __shared__ float tile[64][65];
    int n_in = t & 63;
    int r0 = t >> 6;                       // 0..3
    const float* src = f3d + (size_t)b * NC * NPTS;
#pragma unroll
    for (int r = 0; r < 16; ++r) {
      int c = r0 + (r << 2);
      tile[c][n_in] = src[(size_t)c * NPTS + nt + n_in];
    }
    __syncthreads();
    float* dst = f3dT + ((size_t)b * NPTS + nt) * NC;
    int c_out = t & 63;
#pragma unroll
    for (int r = 0; r < 16; ++r) {
      int n = r0 + (r << 2);
      dst[(size_t)n * NC + c_out] = tile[c_out][n];
    }
  } else {
    int i = (bid - 128) * 256 + t;         // 0..8191
    if (i < NBS * NPTS) {
      int b = i >> 12, n = i & (NPTS - 1);
      float u0 = uv[(size_t)b * 2 * NPTS + n];
      float u1 = uv[(size_t)b * 2 * NPTS + NPTS + n];
      // uu = rnd(rnd(u0^2) + rnd(u1^2)) : matches sum(uv*uv, axis=1)
      // contract(off) guarantees two v_mul + v_add, NO fmac fusion.
      float s0 = u0 * u0;
      float s1 = u1 * u1;
      float uu = s0 + s1;
      pts[i] = make_float4(u0 + u0, u1 + u1, uu, 0.0f);  // 2x exact
    }
  }
}

// ---------------- K1: chunked brute-force 3-NN (branchless, 2 streams) ------
__global__ __launch_bounds__(64) void k1_knn(
    const float4* __restrict__ pts, float2* __restrict__ part) {
#pragma clang fp contract(off)
  int T = blockIdx.x;         // pixel tile
  int ch = blockIdx.y;        // point chunk
  int b = blockIdx.z;
  int lane = threadIdx.x;
  int q = T * 64 + lane;
  float xf = (float)(q % WW);
  float yf = (float)(q / WW);
  // gg = x^2 + y^2 is an exact small integer in fp32
  float gg = xf * xf + yf * yf;

  __shared__ float4 sh[CSZ];               // 4 KiB
  const float4* src = pts + (size_t)b * NPTS + ch * CSZ;
#pragma unroll
  for (int i = 0; i < CSZ / 64; ++i) sh[lane + i * 64] = src[lane + i * 64];
  __syncthreads();

  int base = ch * CSZ;
  // stream A: n in [0,128); stream B: n in [128,256). B indices all > A's,
  // so merging B after A with strict '<' preserves lowest-index tie rule.
  float av0 = FBIG, av1 = FBIG, av2 = FBIG;
  float bv0 = FBIG, bv1 = FBIG, bv2 = FBIG;
  int ai0 = 0, ai1 = 0, ai2 = 0;
  int bi0 = 0, bi1 = 0, bi2 = 0;

#pragma unroll 4
  for (int n = 0; n < CSZ / 2; ++n) {
    float4 pa = sh[n];
    float4 pb = sh[n + CSZ / 2];
    // golden rounding: dot = fma(y,u1, rnd(x*u0)); x2 pre-scale is exact
    float m0a = xf * pa.x;
    float da = (gg + pa.z) - __builtin_fmaf(yf, pa.y, m0a);
    float m0b = xf * pb.x;
    float db = (gg + pb.z) - __builtin_fmaf(yf, pb.y, m0b);
    int gia = base + n;
    int gib = base + n + CSZ / 2;
    // branchless sorted insert (A)
    bool a0 = da < av0, a1 = da < av1, a2 = da < av2;
    ai2 = a1 ? ai1 : (a2 ? gia : ai2);
    ai1 = a0 ? ai0 : (a1 ? gia : ai1);
    ai0 = a0 ? gia : ai0;
    av2 = __builtin_amdgcn_fmed3f(da, av1, av2);
    av1 = __builtin_amdgcn_fmed3f(da, av0, av1);
    av0 = fminf(da, av0);
    // branchless sorted insert (B)
    bool c0 = db < bv0, c1 = db < bv1, c2 = db < bv2;
    bi2 = c1 ? bi1 : (c2 ? gib : bi2);
    bi1 = c0 ? bi0 : (c1 ? gib : bi1);
    bi0 = c0 ? bi0 * 0 + gib : bi0;        // plain select
    bv2 = __builtin_amdgcn_fmed3f(db, bv1, bv2);
    bv1 = __builtin_amdgcn_fmed3f(db, bv0, bv1);
    bv0 = fminf(db, bv0);
  }

  // merge B into A (B sorted ascending, indices ascending among equals)
  float v0 = av0, v1 = av1, v2 = av2;
  int i0 = ai0, i1 = ai1, i2 = ai2;
  INSERT3(bv0, bi0);
  INSERT3(bv1, bi1);
  INSERT3(bv2, bi2);

  size_t row = ((size_t)(b * NTILES + T) * CH + ch) * 3;
  part[(row + 0) * 64 + lane] = make_float2(v0, __int_as_float(i0));
  part[(row + 1) * 64 + lane] = make_float2(v1, __int_as_float(i1));
  part[(row + 2) * 64 + lane] = make_float2(v2, __int_as_float(i2));
}

// ---------------- K2K3 fused: merge + MLP + weighted sum + out-proj ---------
__global__ __launch_bounds__(256) void k2k3(
    const float2* __restrict__ part, const float* __restrict__ uv,
    const float* __restrict__ f3dT,
    const float* __restrict__ w1, const float* __restrict__ b1,
    const float* __restrict__ w2, const float* __restrict__ b2,
    const float* __restrict__ w_out, const float* __restrict__ b_out,
    float* __restrict__ out) {
  int T = blockIdx.x;
  int b = blockIdx.y;
  int t = threadIdx.x;
  int ql = t & 63;                 // query within tile
  int cg = t >> 6;                 // channel group 0..3 (16 ch each)
  int q = T * 64 + ql;
  float xf = (float)(q % WW);
  float yf = (float)(q / WW);

  __shared__ float fin[64][65];

  // ---- merge CH*3 candidates (redundant across the 4 channel groups) ----
  float v0 = FBIG, v1 = FBIG, v2 = FBIG;
  int i0 = 0, i1 = 0, i2 = 0;
  size_t rowBase = (size_t)(b * NTILES + T) * CH * 3;
  for (int c = 0; c < CH * 3; ++c) {
    float2 cnd = part[(rowBase + c) * 64 + ql];
    float d = cnd.x;
    int gi = __float_as_int(cnd.y);
    INSERT3(d, gi);
  }
  int idx[3] = {i0, i1, i2};

  // ---- h1 (redundant across channel groups) ----
  float h1a[3][16];
#pragma unroll
  for (int k = 0; k < 3; ++k) {
    int i = idx[k];
    float u0 = uv[(size_t)b * 2 * NPTS + i];
    float u1 = uv[(size_t)b * 2 * NPTS + NPTS + i];
    float dx = u0 - xf;
    float dy = u1 - yf;
    float nrm = sqrtf(dx * dx + dy * dy);
#pragma unroll
    for (int o = 0; o < 16; ++o) {
      float h = fmaf(w1[o * 3 + 0], dx,
               fmaf(w1[o * 3 + 1], dy,
               fmaf(w1[o * 3 + 2], nrm, b1[o])));
      h1a[k][o] = (h >= 0.0f) ? h : 0.1f * h;
    }
  }

  // ---- my 16 channels: score + weighted feature sum -> LDS ----
  {
    const float4* f0 = (const float4*)(f3dT + ((size_t)b * NPTS + idx[0]) * NC) + cg * 4;
    const float4* f1 = (const float4*)(f3dT + ((size_t)b * NPTS + idx[1]) * NC) + cg * 4;
    const float4* f2 = (const float4*)(f3dT + ((size_t)b * NPTS + idx[2]) * NC) + cg * 4;
#pragma unroll
    for (int c4 = 0; c4 < 4; ++c4) {
      float4 a = f0[c4], bb = f1[c4], cc4 = f2[c4];
      float fa[4] = {a.x, a.y, a.z, a.w};
      float fb[4] = {bb.x, bb.y, bb.z, bb.w};
      float fc[4] = {cc4.x, cc4.y, cc4.z, cc4.w};
#pragma unroll
      for (int cc = 0; cc < 4; ++cc) {
        int c = cg * 16 + c4 * 4 + cc;
        float bias = b2[c];
        float s0 = bias, s1 = bias, s2 = bias;
#pragma unroll
        for (int o = 0; o < 16; ++o) {
          float w = w2[c * 16 + o];
          s0 = fmaf(w, h1a[0][o], s0);
          s1 = fmaf(w, h1a[1][o], s1);
          s2 = fmaf(w, h1a[2][o], s2);
        }
        float g0 = 1.0f / (1.0f + __expf(-s0));
        float g1 = 1.0f / (1.0f + __expf(-s1));
        float g2 = 1.0f / (1.0f + __expf(-s2));
        fin[ql][c] = g0 * fa[cc] + g1 * fb[cc] + g2 * fc[cc];
      }
    }
  }
  __syncthreads();

  // ---- out-projection: 16 output channels per thread ----
  int o0 = cg * 16;
  float acc[16];
#pragma unroll
  for (int j = 0; j < 16; ++j) acc[j] = b_out[o0 + j];
  for (int c = 0; c < 64; ++c) {
    float f = fin[ql][c];
#pragma unroll
    for (int j = 0; j < 16; ++j)
      acc[j] = fmaf(w_out[(o0 + j) * 64 + c], f, acc[j]);
  }
  float* dst = out + ((size_t)(b * 64 + o0)) * HW + T * 64 + ql;
#pragma unroll
  for (int j = 0; j < 16; ++j) {
    float v = acc[j];
    dst[(size_t)j * HW] = (v >= 0.0f) ? v : 0.1f * v;
  }
}

extern "C" void kernel_launch(void* const* d_in, const int* in_sizes, int n_in,
                              void* d_out, int out_size, void* d_ws, size_t ws_size,
                              hipStream_t stream) {
  const float* uv   = (const float*)d_in[0];
  // d_in[1] = feat_2d : values unused by the reference (shape only)
  const float* f3d  = (const float*)d_in[2];
  const float* w1   = (const float*)d_in[3];
  const float* b1   = (const float*)d_in[4];
  const float* w2   = (const float*)d_in[5];
  const float* b2   = (const float*)d_in[6];
  const float* wout = (const float*)d_in[7];
  const float* bout = (const float*)d_in[8];
  float* out = (float*)d_out;

  char* ws = (char*)d_ws;
  float4* pts    = (float4*)(ws);               // 2*4096*16       = 131072 B
  float*  f3dT   = (float*)(ws + 131072);       // 2*4096*64*4     = 2097152 B
  float2* part   = (float2*)(ws + 2228224);     // 2*192*16*3*64*8 = 9437184 B
                                                // total ≈ 11.7 MB

  hipLaunchKernelGGL(k0_prep, dim3(160), dim3(256), 0, stream, uv, f3d, pts, f3dT);
  hipLaunchKernelGGL(k1_knn, dim3(NTILES, CH, NBS), dim3(64), 0, stream, pts, part);
  hipLaunchKernelGGL(k2k3, dim3(NTILES, NBS), dim3(256), 0, stream,
                     part, uv, f3dT, w1, b1, w2, b2, wout, bout, out);
}

// Round 6
// 103.898 us; speedup vs baseline: 1.0150x; 1.0150x over previous
//
#include <hip/hip_runtime.h>
#include <math.h>

#define NBS 2
#define NPTS 4096
#define HH 64
#define WW 192
#define HW (HH*WW)        // 12288
#define NC 64
#define CH 16             // point chunks
#define CSZ (NPTS/CH)     // 256
#define NTILES (HW/64)    // 192

#define FBIG 3.0e38f

// sorted top-3 insert, strict < (ties keep earlier => lower index wins,
// matching lax.top_k stable order, given ascending-index encounter order)
#define INSERT3(dv, gi)                                   \
  if ((dv) < v2) {                                        \
    if ((dv) < v1) {                                      \
      v2 = v1; i2 = i1;                                   \
      if ((dv) < v0) { v1 = v0; i1 = i0; v0 = (dv); i0 = (gi); } \
      else           { v1 = (dv); i1 = (gi); }            \
    } else { v2 = (dv); i2 = (gi); }                      \
  }

// ---------------- K0: pack points (2u0,2u1,uu) + transpose feat_3d ----------
__global__ __launch_bounds__(256) void k0_prep(
    const float* __restrict__ uv, const float* __restrict__ f3d,
    float4* __restrict__ pts, float* __restrict__ f3dT) {
#pragma clang fp contract(off)
  int bid = blockIdx.x;
  int t = threadIdx.x;
  if (bid < 128) {
    // transpose 64n x 64c tile: b = bid/64, ntile = bid%64
    int b = bid >> 6;
    int nt = (bid & 63) << 6;
    __shared__ float tile[64][65];
    int n_in = t & 63;
    int r0 = t >> 6;                       // 0..3
    const float* src = f3d + (size_t)b * NC * NPTS;
#pragma unroll
    for (int r = 0; r < 16; ++r) {
      int c = r0 + (r << 2);
      tile[c][n_in] = src[(size_t)c * NPTS + nt + n_in];
    }
    __syncthreads();
    float* dst = f3dT + ((size_t)b * NPTS + nt) * NC;
    int c_out = t & 63;
#pragma unroll
    for (int r = 0; r < 16; ++r) {
      int n = r0 + (r << 2);
      dst[(size_t)n * NC + c_out] = tile[c_out][n];
    }
  } else {
    int i = (bid - 128) * 256 + t;         // 0..8191
    if (i < NBS * NPTS) {
      int b = i >> 12, n = i & (NPTS - 1);
      float u0 = uv[(size_t)b * 2 * NPTS + n];
      float u1 = uv[(size_t)b * 2 * NPTS + NPTS + n];
      // uu = rnd(rnd(u0^2) + rnd(u1^2)) : matches sum(uv*uv, axis=1)
      // contract(off) guarantees two v_mul + v_add, NO fmac fusion.
      float s0 = u0 * u0;
      float s1 = u1 * u1;
      float uu = s0 + s1;
      pts[i] = make_float4(u0 + u0, u1 + u1, uu, 0.0f);  // 2x exact
    }
  }
}

// ---------------- K1: brute-force 3-NN, 2 queries/lane, LDS-less ------------
// Points are read via wave-uniform addresses -> scalar/broadcast loads, no
// LDS staging, no barriers. Branchless med3 sorted-insert (tie-exact).
__global__ __launch_bounds__(256) void k1_knn(
    const float4* __restrict__ pts, float2* __restrict__ part) {
#pragma clang fp contract(off)
  int bx = blockIdx.x;        // 0..23 : 8 tiles per block
  int ch = blockIdx.y;        // 0..CH-1
  int b = blockIdx.z;
  int t = threadIdx.x;
  int lane = t & 63;
  int w = t >> 6;             // wave 0..3
  int tA = bx * 8 + w;
  int tB = tA + 4;
  int qA = tA * 64 + lane;
  int qB = tB * 64 + lane;
  float xA = (float)(qA % WW), yA = (float)(qA / WW);
  float xB = (float)(qB % WW), yB = (float)(qB / WW);
  float ggA = xA * xA + yA * yA;   // exact small ints
  float ggB = xB * xB + yB * yB;

  const float4* __restrict__ src = pts + (size_t)b * NPTS + ch * CSZ;
  int base = ch * CSZ;

  float av0 = FBIG, av1 = FBIG, av2 = FBIG;
  float bv0 = FBIG, bv1 = FBIG, bv2 = FBIG;
  int ai0 = 0, ai1 = 0, ai2 = 0;
  int bi0 = 0, bi1 = 0, bi2 = 0;

#pragma unroll 4
  for (int n = 0; n < CSZ; ++n) {
    float4 p = src[n];        // wave-uniform address -> s_load / L1 broadcast
    int gi = base + n;
    // golden rounding: d2 = rnd(gg+uu) - 2*fma(y,u1, rnd(x*u0)); x2 pre-scaled
    float dA = (ggA + p.z) - __builtin_fmaf(yA, p.y, xA * p.x);
    float dB = (ggB + p.z) - __builtin_fmaf(yB, p.y, xB * p.x);
    // branchless sorted insert, query A
    bool a0 = dA < av0, a1 = dA < av1, a2 = dA < av2;
    ai2 = a1 ? ai1 : (a2 ? gi : ai2);
    ai1 = a0 ? ai0 : (a1 ? gi : ai1);
    ai0 = a0 ? gi : ai0;
    av2 = __builtin_amdgcn_fmed3f(dA, av1, av2);
    av1 = __builtin_amdgcn_fmed3f(dA, av0, av1);
    av0 = fminf(dA, av0);
    // branchless sorted insert, query B
    bool c0 = dB < bv0, c1 = dB < bv1, c2 = dB < bv2;
    bi2 = c1 ? bi1 : (c2 ? gi : bi2);
    bi1 = c0 ? bi0 : (c1 ? gi : bi1);
    bi0 = c0 ? gi : bi0;
    bv2 = __builtin_amdgcn_fmed3f(dB, bv1, bv2);
    bv1 = __builtin_amdgcn_fmed3f(dB, bv0, bv1);
    bv0 = fminf(dB, bv0);
  }

  size_t rowA = ((size_t)(b * NTILES + tA) * CH + ch) * 3;
  part[(rowA + 0) * 64 + lane] = make_float2(av0, __int_as_float(ai0));
  part[(rowA + 1) * 64 + lane] = make_float2(av1, __int_as_float(ai1));
  part[(rowA + 2) * 64 + lane] = make_float2(av2, __int_as_float(ai2));
  size_t rowB = ((size_t)(b * NTILES + tB) * CH + ch) * 3;
  part[(rowB + 0) * 64 + lane] = make_float2(bv0, __int_as_float(bi0));
  part[(rowB + 1) * 64 + lane] = make_float2(bv1, __int_as_float(bi1));
  part[(rowB + 2) * 64 + lane] = make_float2(bv2, __int_as_float(bi2));
}

// ---------------- K2a: merge CH*3 candidates -> final top-3 indices ---------
__global__ __launch_bounds__(256) void k2a_merge(
    const float2* __restrict__ part, int4* __restrict__ idxOut) {
  int b = blockIdx.y;
  int rem = blockIdx.x * 256 + threadIdx.x;   // 0..12287
  int T = rem >> 6;
  int lane = rem & 63;
  float v0 = FBIG, v1 = FBIG, v2 = FBIG;
  int i0 = 0, i1 = 0, i2 = 0;
  size_t rowBase = (size_t)(b * NTILES + T) * CH * 3;
  // ascending (chunk, rank) order preserves global lowest-index tie rule
  for (int c = 0; c < CH * 3; ++c) {
    float2 cnd = part[(rowBase + c) * 64 + lane];
    float d = cnd.x;
    int gi = __float_as_int(cnd.y);
    INSERT3(d, gi);
  }
  idxOut[(size_t)b * HW + rem] = make_int4(i0, i1, i2, 0);
}

// ---------------- K2b: MLP + weighted sum + out-projection ------------------
// 16 queries x 16 channel-groups (4 ch each) per 256-thread block.
__global__ __launch_bounds__(256) void k2b_mlp(
    const int4* __restrict__ idx4, const float* __restrict__ uv,
    const float* __restrict__ f3dT,
    const float* __restrict__ w1, const float* __restrict__ b1,
    const float* __restrict__ w2, const float* __restrict__ b2,
    const float* __restrict__ w_out, const float* __restrict__ b_out,
    float* __restrict__ out) {
  int blk = blockIdx.x;            // 0..767 : group of 16 queries
  int b = blockIdx.y;
  int t = threadIdx.x;
  int ql = t & 15;                 // query within group
  int cg = t >> 4;                 // channel group 0..15 (4 ch each)
  int q = blk * 16 + ql;
  float xf = (float)(q % WW);
  float yf = (float)(q / WW);

  int4 id4 = idx4[(size_t)b * HW + q];
  int idx[3] = {id4.x, id4.y, id4.z};

  // h1 (redundant across the 16 channel groups; pure VALU, cheap)
  float h1a[3][16];
#pragma unroll
  for (int k = 0; k < 3; ++k) {
    int i = idx[k];
    float u0 = uv[(size_t)b * 2 * NPTS + i];
    float u1 = uv[(size_t)b * 2 * NPTS + NPTS + i];
    float dx = u0 - xf;
    float dy = u1 - yf;
    float nrm = sqrtf(dx * dx + dy * dy);
#pragma unroll
    for (int o = 0; o < 16; ++o) {
      float h = fmaf(w1[o * 3 + 0], dx,
               fmaf(w1[o * 3 + 1], dy,
               fmaf(w1[o * 3 + 2], nrm, b1[o])));
      h1a[k][o] = (h >= 0.0f) ? h : 0.1f * h;
    }
  }

  __shared__ float fin[16][65];

  // my 4 channels: gather 1 float4 per neighbor, score, weighted sum
  {
    float4 f0 = *(const float4*)(f3dT + ((size_t)b * NPTS + idx[0]) * NC + cg * 4);
    float4 f1 = *(const float4*)(f3dT + ((size_t)b * NPTS + idx[1]) * NC + cg * 4);
    float4 f2 = *(const float4*)(f3dT + ((size_t)b * NPTS + idx[2]) * NC + cg * 4);
    float fa[4] = {f0.x, f0.y, f0.z, f0.w};
    float fb[4] = {f1.x, f1.y, f1.z, f1.w};
    float fc[4] = {f2.x, f2.y, f2.z, f2.w};
#pragma unroll
    for (int cc = 0; cc < 4; ++cc) {
      int c = cg * 4 + cc;
      float bias = b2[c];
      float s0 = bias, s1 = bias, s2 = bias;
#pragma unroll
      for (int o = 0; o < 16; ++o) {
        float wv = w2[c * 16 + o];
        s0 = fmaf(wv, h1a[0][o], s0);
        s1 = fmaf(wv, h1a[1][o], s1);
        s2 = fmaf(wv, h1a[2][o], s2);
      }
      float g0 = 1.0f / (1.0f + __expf(-s0));
      float g1 = 1.0f / (1.0f + __expf(-s1));
      float g2 = 1.0f / (1.0f + __expf(-s2));
      fin[ql][c] = g0 * fa[cc] + g1 * fb[cc] + g2 * fc[cc];
    }
  }
  __syncthreads();

  // out-projection: 4 output channels per thread
  int o0 = cg * 4;
  float acc[4];
#pragma unroll
  for (int j = 0; j < 4; ++j) acc[j] = b_out[o0 + j];
  for (int c = 0; c < 64; ++c) {
    float f = fin[ql][c];
#pragma unroll
    for (int j = 0; j < 4; ++j)
      acc[j] = fmaf(w_out[(o0 + j) * 64 + c], f, acc[j]);
  }
  float* dst = out + ((size_t)(b * 64 + o0)) * HW + q;
#pragma unroll
  for (int j = 0; j < 4; ++j) {
    float v = acc[j];
    dst[(size_t)j * HW] = (v >= 0.0f) ? v : 0.1f * v;
  }
}

extern "C" void kernel_launch(void* const* d_in, const int* in_sizes, int n_in,
                              void* d_out, int out_size, void* d_ws, size_t ws_size,
                              hipStream_t stream) {
  const float* uv   = (const float*)d_in[0];
  // d_in[1] = feat_2d : values unused by the reference (shape only)
  const float* f3d  = (const float*)d_in[2];
  const float* w1   = (const float*)d_in[3];
  const float* b1   = (const float*)d_in[4];
  const float* w2   = (const float*)d_in[5];
  const float* b2   = (const float*)d_in[6];
  const float* wout = (const float*)d_in[7];
  const float* bout = (const float*)d_in[8];
  float* out = (float*)d_out;

  char* ws = (char*)d_ws;
  float4* pts    = (float4*)(ws);               // 2*4096*16       = 131072 B
  float*  f3dT   = (float*)(ws + 131072);       // 2*4096*64*4     = 2097152 B
  float2* part   = (float2*)(ws + 2228224);     // 2*192*16*3*64*8 = 9437184 B
  int4*   idx4   = (int4*)(ws + 11665408);      // 2*12288*16      = 393216 B
                                                // total ≈ 11.5 MB

  hipLaunchKernelGGL(k0_prep, dim3(160), dim3(256), 0, stream, uv, f3d, pts, f3dT);
  hipLaunchKernelGGL(k1_knn, dim3(24, CH, NBS), dim3(256), 0, stream, pts, part);
  hipLaunchKernelGGL(k2a_merge, dim3(48, NBS), dim3(256), 0, stream, part, idx4);
  hipLaunchKernelGGL(k2b_mlp, dim3(HW / 16, NBS), dim3(256), 0, stream,
                     (const int4*)idx4, uv, f3dT, w1, b1, w2, b2, wout, bout, out);
}

// Round 7
// 52.848 us; speedup vs baseline: 1.9955x; 1.9660x over previous
//
#include <hip/hip_runtime.h>
#include <math.h>

#define NBS 2
#define NPTS 4096
#define HH 64
#define WW 192
#define HW (HH*WW)        // 12288
#define NC 64
#define GX 24             // cells in x (8 px each)
#define GY 8              // cells in y
#define NCELL (GX*GY)     // 192

#define FBIG 3.0e38f

// ---------------- K0: transpose feat_3d (blocks 0..127) + bin points --------
__global__ __launch_bounds__(256) void k0_prep(
    const float* __restrict__ uv, const float* __restrict__ f3d,
    float* __restrict__ f3dT, float4* __restrict__ binned,
    int* __restrict__ cellStart) {
#pragma clang fp contract(off)
  int bid = blockIdx.x;
  int t = threadIdx.x;
  if (bid < 128) {
    // transpose 64n x 64c tile: b = bid/64, ntile = bid%64
    int b = bid >> 6;
    int nt = (bid & 63) << 6;
    __shared__ float tile[64][65];
    int n_in = t & 63;
    int r0 = t >> 6;                       // 0..3
    const float* src = f3d + (size_t)b * NC * NPTS;
#pragma unroll
    for (int r = 0; r < 16; ++r) {
      int c = r0 + (r << 2);
      tile[c][n_in] = src[(size_t)c * NPTS + nt + n_in];
    }
    __syncthreads();
    float* dst = f3dT + ((size_t)b * NPTS + nt) * NC;
    int c_out = t & 63;
#pragma unroll
    for (int r = 0; r < 16; ++r) {
      int n = r0 + (r << 2);
      dst[(size_t)n * NC + c_out] = tile[c_out][n];
    }
  } else {
    // counting-sort bin for batch b = bid-128 (single block does all 4096)
    int b = bid - 128;
    __shared__ int hist[NCELL + 1];
    __shared__ int cur[NCELL];
    if (t < NCELL + 1) hist[t] = 0;
    __syncthreads();
    const float* u0p = uv + (size_t)b * 2 * NPTS;
    const float* u1p = u0p + NPTS;
    for (int n = t; n < NPTS; n += 256) {
      float u0 = u0p[n], u1 = u1p[n];
      int cxp = min((int)(u0 * 0.125f), GX - 1);   // u*0.125f exact (pow2)
      int cyp = min((int)(u1 * 0.125f), GY - 1);
      atomicAdd(&hist[cyp * GX + cxp + 1], 1);
    }
    __syncthreads();
    if (t == 0) {
      int acc = 0;
      for (int c = 1; c <= NCELL; ++c) { acc += hist[c]; hist[c] = acc; }
    }
    __syncthreads();
    if (t < NCELL) cur[t] = hist[t];
    if (t <= NCELL) cellStart[b * 200 + t] = hist[t];
    __syncthreads();
    for (int n = t; n < NPTS; n += 256) {
      float u0 = u0p[n], u1 = u1p[n];
      // golden rounding: uu = rnd(rnd(u0^2)+rnd(u1^2)), contract(off) = no fma
      float s0 = u0 * u0;
      float s1 = u1 * u1;
      float uu = s0 + s1;
      int cxp = min((int)(u0 * 0.125f), GX - 1);
      int cyp = min((int)(u1 * 0.125f), GY - 1);
      int pos = atomicAdd(&cur[cyp * GX + cxp], 1);
      binned[(size_t)b * NPTS + pos] =
          make_float4(u0 + u0, u1 + u1, uu, __int_as_float(n));
    }
  }
}

// ---------------- K1: binned 3-NN, 8 lanes/query, lex (d,idx) smallest-3 ----
// Lex order makes selection independent of candidate encounter order, and is
// set-identical to stable lax.top_k (lowest index wins ties).
__global__ __launch_bounds__(256) void k1_knn(
    const float4* __restrict__ binned, const int* __restrict__ cellStart,
    int4* __restrict__ idxOut) {
#pragma clang fp contract(off)
  int t = threadIdx.x;
  int j = t & 7;                       // splitter lane 0..7
  int qi = blockIdx.x * 32 + (t >> 3); // query id
  int b = blockIdx.y;
  int x = qi % WW, y = qi / WW;
  float xf = (float)x, yf = (float)y;
  float gg = xf * xf + yf * yf;        // exact small ints
  int cx = x >> 3, cy = y >> 3;

  const float4* __restrict__ pts = binned + (size_t)b * NPTS;
  const int* __restrict__ cs = cellStart + b * 200;

  float v0 = FBIG, v1 = FBIG, v2 = FBIG;
  int i0 = 0x7FFFFFFF, i1 = 0x7FFFFFFF, i2 = 0x7FFFFFFF;

  auto ins = [&](float d, int gi) {
    bool lt2 = (d < v2) || (d == v2 && gi < i2);
    bool lt1 = (d < v1) || (d == v1 && gi < i1);
    bool lt0 = (d < v0) || (d == v0 && gi < i0);
    i2 = lt1 ? i1 : (lt2 ? gi : i2);
    v2 = lt1 ? v1 : (lt2 ? d : v2);
    i1 = lt0 ? i0 : (lt1 ? gi : i1);
    v1 = lt0 ? v0 : (lt1 ? d : v1);
    i0 = lt0 ? gi : i0;
    v0 = lt0 ? d : v0;
  };
  auto scanRow = [&](int ry, int cA, int cB) {
    int s = cs[ry * GX + cA];
    int e = cs[ry * GX + cB + 1];      // cells row-contiguous -> one segment
    for (int n = s + j; n < e; n += 8) {
      float4 p = pts[n];
      // golden: d2 = rnd(gg+uu) - 2*fma(y,u1, rnd(x*u0)); x2 pre-scaled exact
      float d = (gg + p.z) - __builtin_fmaf(yf, p.y, xf * p.x);
      ins(d, __float_as_int(p.w));
    }
  };
  auto mergeAll = [&]() {
#pragma unroll
    for (int m = 1; m <= 4; m <<= 1) {
      float ov0 = __shfl_xor(v0, m), ov1 = __shfl_xor(v1, m),
            ov2 = __shfl_xor(v2, m);
      int oi0 = __shfl_xor(i0, m), oi1 = __shfl_xor(i1, m),
          oi2 = __shfl_xor(i2, m);
      ins(ov0, oi0); ins(ov1, oi1); ins(ov2, oi2);
    }
  };

  int cxL = max(cx - 1, 0), cxH = min(cx + 1, GX - 1);
  int cyL = max(cy - 1, 0), cyH = min(cy + 1, GY - 1);
  for (int ry = cyL; ry <= cyH; ++ry) scanRow(ry, cxL, cxH);
  mergeAll();

  // ring expansion: statistically never taken (dmin>=8 => dmin^2-4 >= 60 >>
  // typical r3^2 ~ 3), but guarantees exactness incl. rounded-d2 skew (<=0.1).
  while (true) {
    bool fullDom = (cxL == 0 && cxH == GX - 1 && cyL == 0 && cyH == GY - 1);
    float dL = (cxL > 0) ? (xf - (float)(cxL * 8)) : FBIG;
    float dR = (cxH < GX - 1) ? ((float)((cxH + 1) * 8) - xf) : FBIG;
    float dB = (cyL > 0) ? (yf - (float)(cyL * 8)) : FBIG;
    float dT = (cyH < GY - 1) ? ((float)((cyH + 1) * 8) - yf) : FBIG;
    float dmin = fminf(fminf(dL, dR), fminf(dB, dT));
    if (fullDom || (v2 < dmin * dmin - 4.0f)) break;
    int nxL = max(cxL - 1, 0), nxH = min(cxH + 1, GX - 1);
    int nyL = max(cyL - 1, 0), nyH = min(cyH + 1, GY - 1);
    for (int ry = nyL; ry <= nyH; ++ry) {
      if (ry < cyL || ry > cyH) scanRow(ry, nxL, nxH);
      else {
        if (nxL < cxL) scanRow(ry, nxL, cxL - 1);
        if (nxH > cxH) scanRow(ry, cxH + 1, nxH);
      }
    }
    cxL = nxL; cxH = nxH; cyL = nyL; cyH = nyH;
    mergeAll();
  }

  if (j == 0) idxOut[(size_t)b * HW + qi] = make_int4(i0, i1, i2, 0);
}

// ---------------- K2b: MLP + weighted sum + out-projection ------------------
// 16 queries x 16 channel-groups (4 ch each) per 256-thread block.
__global__ __launch_bounds__(256) void k2b_mlp(
    const int4* __restrict__ idx4, const float* __restrict__ uv,
    const float* __restrict__ f3dT,
    const float* __restrict__ w1, const float* __restrict__ b1,
    const float* __restrict__ w2, const float* __restrict__ b2,
    const float* __restrict__ w_out, const float* __restrict__ b_out,
    float* __restrict__ out) {
  int blk = blockIdx.x;            // group of 16 queries
  int b = blockIdx.y;
  int t = threadIdx.x;
  int ql = t & 15;                 // query within group
  int cg = t >> 4;                 // channel group 0..15 (4 ch each)
  int q = blk * 16 + ql;
  float xf = (float)(q % WW);
  float yf = (float)(q / WW);

  int4 id4 = idx4[(size_t)b * HW + q];
  int idx[3] = {id4.x, id4.y, id4.z};

  // h1 (redundant across the 16 channel groups; pure VALU, cheap)
  float h1a[3][16];
#pragma unroll
  for (int k = 0; k < 3; ++k) {
    int i = idx[k];
    float u0 = uv[(size_t)b * 2 * NPTS + i];
    float u1 = uv[(size_t)b * 2 * NPTS + NPTS + i];
    float dx = u0 - xf;
    float dy = u1 - yf;
    float nrm = sqrtf(dx * dx + dy * dy);
#pragma unroll
    for (int o = 0; o < 16; ++o) {
      float h = fmaf(w1[o * 3 + 0], dx,
               fmaf(w1[o * 3 + 1], dy,
               fmaf(w1[o * 3 + 2], nrm, b1[o])));
      h1a[k][o] = (h >= 0.0f) ? h : 0.1f * h;
    }
  }

  __shared__ float fin[16][65];

  // my 4 channels: gather 1 float4 per neighbor, score, weighted sum
  {
    float4 f0 = *(const float4*)(f3dT + ((size_t)b * NPTS + idx[0]) * NC + cg * 4);
    float4 f1 = *(const float4*)(f3dT + ((size_t)b * NPTS + idx[1]) * NC + cg * 4);
    float4 f2 = *(const float4*)(f3dT + ((size_t)b * NPTS + idx[2]) * NC + cg * 4);
    float fa[4] = {f0.x, f0.y, f0.z, f0.w};
    float fb[4] = {f1.x, f1.y, f1.z, f1.w};
    float fc[4] = {f2.x, f2.y, f2.z, f2.w};
#pragma unroll
    for (int cc = 0; cc < 4; ++cc) {
      int c = cg * 4 + cc;
      float bias = b2[c];
      float s0 = bias, s1 = bias, s2 = bias;
#pragma unroll
      for (int o = 0; o < 16; ++o) {
        float wv = w2[c * 16 + o];
        s0 = fmaf(wv, h1a[0][o], s0);
        s1 = fmaf(wv, h1a[1][o], s1);
        s2 = fmaf(wv, h1a[2][o], s2);
      }
      float g0 = 1.0f / (1.0f + __expf(-s0));
      float g1 = 1.0f / (1.0f + __expf(-s1));
      float g2 = 1.0f / (1.0f + __expf(-s2));
      fin[ql][c] = g0 * fa[cc] + g1 * fb[cc] + g2 * fc[cc];
    }
  }
  __syncthreads();

  // out-projection: 4 output channels per thread
  int o0 = cg * 4;
  float acc[4];
#pragma unroll
  for (int jj = 0; jj < 4; ++jj) acc[jj] = b_out[o0 + jj];
  for (int c = 0; c < 64; ++c) {
    float f = fin[ql][c];
#pragma unroll
    for (int jj = 0; jj < 4; ++jj)
      acc[jj] = fmaf(w_out[(o0 + jj) * 64 + c], f, acc[jj]);
  }
  float* dst = out + ((size_t)(b * 64 + o0)) * HW + q;
#pragma unroll
  for (int jj = 0; jj < 4; ++jj) {
    float v = acc[jj];
    dst[(size_t)jj * HW] = (v >= 0.0f) ? v : 0.1f * v;
  }
}

extern "C" void kernel_launch(void* const* d_in, const int* in_sizes, int n_in,
                              void* d_out, int out_size, void* d_ws, size_t ws_size,
                              hipStream_t stream) {
  const float* uv   = (const float*)d_in[0];
  // d_in[1] = feat_2d : values unused by the reference (shape only)
  const float* f3d  = (const float*)d_in[2];
  const float* w1   = (const float*)d_in[3];
  const float* b1   = (const float*)d_in[4];
  const float* w2   = (const float*)d_in[5];
  const float* b2   = (const float*)d_in[6];
  const float* wout = (const float*)d_in[7];
  const float* bout = (const float*)d_in[8];
  float* out = (float*)d_out;

  char* ws = (char*)d_ws;
  float*  f3dT      = (float*)(ws);             // 2*4096*64*4 = 2097152 B
  float4* binned    = (float4*)(ws + 2097152);  // 2*4096*16   = 131072 B
  int*    cellStart = (int*)(ws + 2228224);     // 2*200*4     = 1600 B
  int4*   idx4      = (int4*)(ws + 2232320);    // 2*12288*16  = 393216 B
                                                // total ≈ 2.63 MB

  hipLaunchKernelGGL(k0_prep, dim3(130), dim3(256), 0, stream,
                     uv, f3d, f3dT, binned, cellStart);
  hipLaunchKernelGGL(k1_knn, dim3(HW / 32, NBS), dim3(256), 0, stream,
                     (const float4*)binned, (const int*)cellStart, idx4);
  hipLaunchKernelGGL(k2b_mlp, dim3(HW / 16, NBS), dim3(256), 0, stream,
                     (const int4*)idx4, uv, f3dT, w1, b1, w2, b2, wout, bout, out);
}

// Round 8
// 50.490 us; speedup vs baseline: 2.0886x; 1.0467x over previous
//
#include <hip/hip_runtime.h>
#include <math.h>

#define NBS 2
#define NPTS 4096
#define HH 64
#define WW 192
#define HW (HH*WW)        // 12288
#define NC 64
#define GX 24             // cells in x (8 px each)
#define GY 8              // cells in y
#define NCELL (GX*GY)     // 192

#define FBIG 3.0e38f

// ---------------- K0: transpose feat_3d (blocks 0..127) + bin points --------
__global__ __launch_bounds__(256) void k0_prep(
    const float* __restrict__ uv, const float* __restrict__ f3d,
    float* __restrict__ f3dT, float4* __restrict__ binned,
    int* __restrict__ cellStart) {
#pragma clang fp contract(off)
  int bid = blockIdx.x;
  int t = threadIdx.x;
  if (bid < 128) {
    // transpose 64n x 64c tile: b = bid/64, ntile = bid%64
    int b = bid >> 6;
    int nt = (bid & 63) << 6;
    __shared__ float tile[64][65];
    int n_in = t & 63;
    int r0 = t >> 6;                       // 0..3
    const float* src = f3d + (size_t)b * NC * NPTS;
#pragma unroll
    for (int r = 0; r < 16; ++r) {
      int c = r0 + (r << 2);
      tile[c][n_in] = src[(size_t)c * NPTS + nt + n_in];
    }
    __syncthreads();
    float* dst = f3dT + ((size_t)b * NPTS + nt) * NC;
    int c_out = t & 63;
#pragma unroll
    for (int r = 0; r < 16; ++r) {
      int n = r0 + (r << 2);
      dst[(size_t)n * NC + c_out] = tile[c_out][n];
    }
  } else {
    // counting-sort bin for batch b = bid-128 (single block does all 4096)
    int b = bid - 128;
    __shared__ int hist[NCELL + 1];
    __shared__ int cur[NCELL];
    if (t <= NCELL) hist[t] = 0;
    __syncthreads();
    const float* u0p = uv + (size_t)b * 2 * NPTS;
    const float* u1p = u0p + NPTS;
    for (int n = t; n < NPTS; n += 256) {
      float u0 = u0p[n], u1 = u1p[n];
      int cxp = min((int)(u0 * 0.125f), GX - 1);   // u*0.125f exact (pow2)
      int cyp = min((int)(u1 * 0.125f), GY - 1);
      atomicAdd(&hist[cyp * GX + cxp + 1], 1);
    }
    __syncthreads();
    // parallel Hillis-Steele inclusive scan over hist[0..NCELL]
    for (int off = 1; off <= NCELL; off <<= 1) {
      int v = 0;
      if (t <= NCELL && t >= off) v = hist[t - off];
      __syncthreads();
      if (t <= NCELL && t >= off) hist[t] += v;
      __syncthreads();
    }
    if (t < NCELL) cur[t] = hist[t];
    if (t <= NCELL) cellStart[b * 200 + t] = hist[t];
    __syncthreads();
    for (int n = t; n < NPTS; n += 256) {
      float u0 = u0p[n], u1 = u1p[n];
      // golden rounding: uu = rnd(rnd(u0^2)+rnd(u1^2)), contract(off) = no fma
      float s0 = u0 * u0;
      float s1 = u1 * u1;
      float uu = s0 + s1;
      int cxp = min((int)(u0 * 0.125f), GX - 1);
      int cyp = min((int)(u1 * 0.125f), GY - 1);
      int pos = atomicAdd(&cur[cyp * GX + cxp], 1);
      binned[(size_t)b * NPTS + pos] =
          make_float4(u0 + u0, u1 + u1, uu, __int_as_float(n));
    }
  }
}

// ---------------- K_MAIN: fused binned 3-NN + MLP + out-projection ----------
// Block = 16 queries x 256 threads. Phase 1: KNN, 16 lanes/query, lex (d,idx)
// smallest-3 (order-independent, == stable lax.top_k set). Phase 2: MLP+proj.
__global__ __launch_bounds__(256) void k_main(
    const float4* __restrict__ binned, const int* __restrict__ cellStart,
    const float* __restrict__ uv, const float* __restrict__ f3dT,
    const float* __restrict__ w1, const float* __restrict__ b1,
    const float* __restrict__ w2, const float* __restrict__ b2,
    const float* __restrict__ w_out, const float* __restrict__ b_out,
    float* __restrict__ out) {
#pragma clang fp contract(off)
  int t = threadIdx.x;
  int b = blockIdx.y;

  __shared__ int sidx[16][4];
  __shared__ float fin[16][68];   // row stride 68 floats = 272 B (16B-aligned)

  // ===== phase 1: KNN =====
  {
    int Q = t >> 4;                      // query slot 0..15 (16 lanes each,
    int j = t & 15;                      //  contiguous within a wave)
    int qi = blockIdx.x * 16 + Q;
    int x = qi % WW, y = qi / WW;
    float xf = (float)x, yf = (float)y;
    float gg = xf * xf + yf * yf;        // exact small ints
    int cx = x >> 3, cy = y >> 3;

    const float4* __restrict__ pts = binned + (size_t)b * NPTS;
    const int* __restrict__ cs = cellStart + b * 200;

    float v0 = FBIG, v1 = FBIG, v2 = FBIG;
    int i0 = 0x7FFFFFFF, i1 = 0x7FFFFFFF, i2 = 0x7FFFFFFF;

    auto ins = [&](float d, int gi) {
      bool lt2 = (d < v2) || (d == v2 && gi < i2);
      bool lt1 = (d < v1) || (d == v1 && gi < i1);
      bool lt0 = (d < v0) || (d == v0 && gi < i0);
      i2 = lt1 ? i1 : (lt2 ? gi : i2);
      v2 = lt1 ? v1 : (lt2 ? d : v2);
      i1 = lt0 ? i0 : (lt1 ? gi : i1);
      v1 = lt0 ? v0 : (lt1 ? d : v1);
      i0 = lt0 ? gi : i0;
      v0 = lt0 ? d : v0;
    };
    auto scanRow = [&](int ry, int cA, int cB) {
      int s = cs[ry * GX + cA];
      int e = cs[ry * GX + cB + 1];      // cells row-contiguous -> one segment
      for (int n = s + j; n < e; n += 16) {
        float4 p = pts[n];
        // golden: d2 = rnd(gg+uu) - 2*fma(y,u1, rnd(x*u0)); x2 pre-scaled
        float d = (gg + p.z) - __builtin_fmaf(yf, p.y, xf * p.x);
        ins(d, __float_as_int(p.w));
      }
    };
    auto mergeAll = [&]() {
#pragma unroll
      for (int m = 1; m <= 8; m <<= 1) {
        float ov0 = __shfl_xor(v0, m), ov1 = __shfl_xor(v1, m),
              ov2 = __shfl_xor(v2, m);
        int oi0 = __shfl_xor(i0, m), oi1 = __shfl_xor(i1, m),
            oi2 = __shfl_xor(i2, m);
        ins(ov0, oi0); ins(ov1, oi1); ins(ov2, oi2);
      }
    };

    int cxL = max(cx - 1, 0), cxH = min(cx + 1, GX - 1);
    int cyL = max(cy - 1, 0), cyH = min(cy + 1, GY - 1);
    for (int ry = cyL; ry <= cyH; ++ry) scanRow(ry, cxL, cxH);
    mergeAll();

    // ring expansion: statistically never taken (dmin>=8 => dmin^2-4 >= 60 >>
    // typical r3^2 ~ 3) but guarantees exactness incl. rounded-d2 skew (<=0.1)
    while (true) {
      bool fullDom = (cxL == 0 && cxH == GX - 1 && cyL == 0 && cyH == GY - 1);
      float dL = (cxL > 0) ? (xf - (float)(cxL * 8)) : FBIG;
      float dR = (cxH < GX - 1) ? ((float)((cxH + 1) * 8) - xf) : FBIG;
      float dB = (cyL > 0) ? (yf - (float)(cyL * 8)) : FBIG;
      float dT = (cyH < GY - 1) ? ((float)((cyH + 1) * 8) - yf) : FBIG;
      float dmin = fminf(fminf(dL, dR), fminf(dB, dT));
      if (fullDom || (v2 < dmin * dmin - 4.0f)) break;
      int nxL = max(cxL - 1, 0), nxH = min(cxH + 1, GX - 1);
      int nyL = max(cyL - 1, 0), nyH = min(cyH + 1, GY - 1);
      for (int ry = nyL; ry <= nyH; ++ry) {
        if (ry < cyL || ry > cyH) scanRow(ry, nxL, nxH);
        else {
          if (nxL < cxL) scanRow(ry, nxL, cxL - 1);
          if (nxH > cxH) scanRow(ry, cxH + 1, nxH);
        }
      }
      cxL = nxL; cxH = nxH; cyL = nyL; cyH = nyH;
      mergeAll();
    }

    if (j == 0) { sidx[Q][0] = i0; sidx[Q][1] = i1; sidx[Q][2] = i2; }
  }
  __syncthreads();

  // ===== phase 2: MLP + weighted sum =====
  int ql = t & 15;                 // query within group
  int cg = t >> 4;                 // channel group 0..15 (4 ch each)
  int q = blockIdx.x * 16 + ql;
  float xf = (float)(q % WW);
  float yf = (float)(q / WW);
  int idx[3] = {sidx[ql][0], sidx[ql][1], sidx[ql][2]};

  // h1 (redundant across the 16 channel groups; pure VALU)
  float h1a[3][16];
#pragma unroll
  for (int k = 0; k < 3; ++k) {
    int i = idx[k];
    float u0 = uv[(size_t)b * 2 * NPTS + i];
    float u1 = uv[(size_t)b * 2 * NPTS + NPTS + i];
    float dx = u0 - xf;
    float dy = u1 - yf;
    float nrm = sqrtf(__builtin_fmaf(dx, dx, dy * dy));
#pragma unroll
    for (int o = 0; o < 16; ++o) {
      float h = fmaf(w1[o * 3 + 0], dx,
               fmaf(w1[o * 3 + 1], dy,
               fmaf(w1[o * 3 + 2], nrm, b1[o])));
      h1a[k][o] = (h >= 0.0f) ? h : 0.1f * h;
    }
  }

  // my 4 channels: gather 1 float4 per neighbor, score via w2 (float4 loads)
  {
    float4 f0 = *(const float4*)(f3dT + ((size_t)b * NPTS + idx[0]) * NC + cg * 4);
    float4 f1 = *(const float4*)(f3dT + ((size_t)b * NPTS + idx[1]) * NC + cg * 4);
    float4 f2 = *(const float4*)(f3dT + ((size_t)b * NPTS + idx[2]) * NC + cg * 4);
    float fa[4] = {f0.x, f0.y, f0.z, f0.w};
    float fb[4] = {f1.x, f1.y, f1.z, f1.w};
    float fc[4] = {f2.x, f2.y, f2.z, f2.w};
#pragma unroll
    for (int cc = 0; cc < 4; ++cc) {
      int c = cg * 4 + cc;
      float bias = b2[c];
      float s0 = bias, s1 = bias, s2 = bias;
      const float4* w2r = (const float4*)(w2 + c * 16);
#pragma unroll
      for (int o4 = 0; o4 < 4; ++o4) {
        float4 wv = w2r[o4];
        float wvs[4] = {wv.x, wv.y, wv.z, wv.w};
#pragma unroll
        for (int oo = 0; oo < 4; ++oo) {
          int o = o4 * 4 + oo;
          s0 = fmaf(wvs[oo], h1a[0][o], s0);
          s1 = fmaf(wvs[oo], h1a[1][o], s1);
          s2 = fmaf(wvs[oo], h1a[2][o], s2);
        }
      }
      float g0 = 1.0f / (1.0f + __expf(-s0));
      float g1 = 1.0f / (1.0f + __expf(-s1));
      float g2 = 1.0f / (1.0f + __expf(-s2));
      fin[ql][c] = fmaf(g0, fa[cc], fmaf(g1, fb[cc], g2 * fc[cc]));
    }
  }
  __syncthreads();

  // ===== phase 3: out-projection, 4 output channels per thread ============
  int o0 = cg * 4;
  float acc[4];
#pragma unroll
  for (int jj = 0; jj < 4; ++jj) acc[jj] = b_out[o0 + jj];
  const float4* finq = (const float4*)(&fin[ql][0]);
#pragma unroll 4
  for (int c4 = 0; c4 < 16; ++c4) {
    float4 f = finq[c4];
#pragma unroll
    for (int jj = 0; jj < 4; ++jj) {
      float4 wv = *(const float4*)(w_out + (o0 + jj) * 64 + c4 * 4);
      acc[jj] = fmaf(wv.x, f.x,
                fmaf(wv.y, f.y,
                fmaf(wv.z, f.z,
                fmaf(wv.w, f.w, acc[jj]))));
    }
  }
  float* dst = out + ((size_t)(b * 64 + o0)) * HW + q;
#pragma unroll
  for (int jj = 0; jj < 4; ++jj) {
    float v = acc[jj];
    dst[(size_t)jj * HW] = (v >= 0.0f) ? v : 0.1f * v;
  }
}

extern "C" void kernel_launch(void* const* d_in, const int* in_sizes, int n_in,
                              void* d_out, int out_size, void* d_ws, size_t ws_size,
                              hipStream_t stream) {
  const float* uv   = (const float*)d_in[0];
  // d_in[1] = feat_2d : values unused by the reference (shape only)
  const float* f3d  = (const float*)d_in[2];
  const float* w1   = (const float*)d_in[3];
  const float* b1   = (const float*)d_in[4];
  const float* w2   = (const float*)d_in[5];
  const float* b2   = (const float*)d_in[6];
  const float* wout = (const float*)d_in[7];
  const float* bout = (const float*)d_in[8];
  float* out = (float*)d_out;

  char* ws = (char*)d_ws;
  float*  f3dT      = (float*)(ws);             // 2*4096*64*4 = 2097152 B
  float4* binned    = (float4*)(ws + 2097152);  // 2*4096*16   = 131072 B
  int*    cellStart = (int*)(ws + 2228224);     // 2*200*4     = 1600 B
                                                // total ≈ 2.23 MB

  hipLaunchKernelGGL(k0_prep, dim3(130), dim3(256), 0, stream,
                     uv, f3d, f3dT, binned, cellStart);
  hipLaunchKernelGGL(k_main, dim3(HW / 16, NBS), dim3(256), 0, stream,
                     (const float4*)binned, (const int*)cellStart,
                     uv, f3dT, w1, b1, w2, b2, wout, bout, out);
}